// Round 1
// baseline (527.576 us; speedup 1.0000x reference)
//
#include <hip/hip_runtime.h>
#include <float.h>
#include <math.h>

// VQ-VAE VectorQuantizer fused kernel set (round 1: fp32 VALU, correctness-first)
//
// z_e: (32, 256, 32, 32) fp32, weight: (1024, 256) fp32
// outputs concat: quantized_st (8388608) + loss (1) + perplexity (1)
//
// ws layout (bytes): [0,4096) wsq (1024 f32) | [4096,8192) counts (1024 u32)
//                    [8192,8196) loss_sum (f32)

#define NB   32
#define NC   256
#define NHW  1024
#define NK   1024
#define NELEM (NB*NC*NHW)   // 8388608

// ---------------- K1: codebook row squared norms ----------------
__global__ __launch_bounds__(256) void vq_wsq(const float* __restrict__ w,
                                              float* __restrict__ wsq) {
    const int lane = threadIdx.x & 63;
    const int wave = threadIdx.x >> 6;          // 0..3
    const int k = blockIdx.x * 4 + wave;        // grid = 256 blocks -> k 0..1023
    const float* row = w + k * NC;
    float s = 0.f;
#pragma unroll
    for (int p = 0; p < 4; ++p) {
        float v = row[lane + p * 64];
        s = fmaf(v, v, s);
    }
#pragma unroll
    for (int off = 32; off; off >>= 1) s += __shfl_down(s, off, 64);
    if (lane == 0) wsq[k] = s;
}

// ---------------- K2: fused argmin + gather + loss + histogram ----------------
// grid: 512 blocks, each handles 64 consecutive hw positions of one batch image.
// block: 256 threads = (tx 0..15 code-groups) x (ty 0..15 row-groups), 4x4 regs.
__global__ __launch_bounds__(256) void vq_main(const float* __restrict__ z,
                                               const float* __restrict__ w,
                                               const float* __restrict__ wsq,
                                               unsigned int* __restrict__ counts,
                                               float* __restrict__ loss_sum,
                                               float* __restrict__ out) {
    __shared__ __align__(16) float Zs[32][64];   // [c][hw]  8 KB
    __shared__ __align__(16) float Ws[32][68];   // [c][k] padded (+4 keeps 16B align) 8.7 KB
    __shared__ float cv[64][17];
    __shared__ int   ci[64][17];
    __shared__ int   fidx[64];
    __shared__ float wsum[4];

    const int tid = threadIdx.x;
    const int tx = tid & 15;
    const int ty = tid >> 4;
    const int t = blockIdx.x;
    const int bidx = t >> 4;                 // batch 0..31
    const int hw0  = (t & 15) << 6;          // hw tile origin
    const float* zb = z + bidx * (NC * NHW) + hw0;

    float bestv[4] = {FLT_MAX, FLT_MAX, FLT_MAX, FLT_MAX};
    int   besti[4] = {0, 0, 0, 0};

    for (int kt = 0; kt < 16; ++kt) {        // 16 code tiles of 64
        const int k0 = kt * 64;
        float acc[4][4] = {};
        for (int cc = 0; cc < 8; ++cc) {     // 8 c-chunks of 32
            __syncthreads();
            {   // stage Z chunk: 32 c x 64 hw, coalesced (lane -> hw)
                const int hwl = tid & 63;
                const int cl0 = tid >> 6;    // 0..3
#pragma unroll
                for (int p = 0; p < 8; ++p) {
                    const int cl = p * 4 + cl0;
                    Zs[cl][hwl] = zb[(cc * 32 + cl) * NHW + hwl];
                }
            }
            {   // stage W chunk transposed: Ws[c][k]
                const int cl  = tid & 31;
                const int kl0 = tid >> 5;    // 0..7
#pragma unroll
                for (int p = 0; p < 8; ++p) {
                    const int kl = p * 8 + kl0;
                    Ws[cl][kl] = w[(k0 + kl) * NC + cc * 32 + cl];
                }
            }
            __syncthreads();
#pragma unroll 8
            for (int c = 0; c < 32; ++c) {
                const float4 z4 = *(const float4*)(&Zs[c][ty << 2]);
                const float4 w4 = *(const float4*)(&Ws[c][tx << 2]);
                const float zr[4] = {z4.x, z4.y, z4.z, z4.w};
                const float wr[4] = {w4.x, w4.y, w4.z, w4.w};
#pragma unroll
                for (int i = 0; i < 4; ++i)
#pragma unroll
                    for (int j = 0; j < 4; ++j)
                        acc[i][j] = fmaf(zr[i], wr[j], acc[i][j]);
            }
        }
        // fold this code tile into running per-thread best
#pragma unroll
        for (int j = 0; j < 4; ++j) {
            const int kk = k0 + tx * 4 + j;
            const float wq = wsq[kk];
#pragma unroll
            for (int i = 0; i < 4; ++i) {
                const float s = fmaf(-2.f, acc[i][j], wq);
                if (s < bestv[i]) { bestv[i] = s; besti[i] = kk; }
            }
        }
    }

    // cross-tx reduction: 16 candidates per row
#pragma unroll
    for (int i = 0; i < 4; ++i) {
        cv[ty * 4 + i][tx] = bestv[i];
        ci[ty * 4 + i][tx] = besti[i];
    }
    __syncthreads();
    if (tid < 64) {
        float bv = cv[tid][0];
        int   bi = ci[tid][0];
#pragma unroll
        for (int x = 1; x < 16; ++x) {
            const float v = cv[tid][x];
            if (v < bv) { bv = v; bi = ci[tid][x]; }
        }
        fidx[tid] = bi;
        atomicAdd(&counts[bi], 1u);
    }
    __syncthreads();

    // phase 2: gather codebook rows, write quantized_st, accumulate loss
    float lsum = 0.f;
    const int hwl = tid & 63;
    const int cq  = tid >> 6;                 // 0..3
    const int myk = fidx[hwl];
    const float* wrow = w + myk * NC;
    float* ob = out + bidx * (NC * NHW) + hw0;
#pragma unroll 4
    for (int p = 0; p < 64; ++p) {
        const int c = p * 4 + cq;
        const float q  = wrow[c];
        const float zv = zb[c * NHW + hwl];
        const float d  = q - zv;
        lsum = fmaf(d, d, lsum);
        ob[c * NHW + hwl] = q;
    }
#pragma unroll
    for (int off = 32; off; off >>= 1) lsum += __shfl_down(lsum, off, 64);
    if ((tid & 63) == 0) wsum[tid >> 6] = lsum;
    __syncthreads();
    if (tid == 0) atomicAdd(loss_sum, wsum[0] + wsum[1] + wsum[2] + wsum[3]);
}

// ---------------- K3: finalize loss + perplexity ----------------
__global__ __launch_bounds__(256) void vq_final(const unsigned int* __restrict__ counts,
                                                const float* __restrict__ loss_sum,
                                                float* __restrict__ out) {
    __shared__ float red[4];
    const int tid = threadIdx.x;
    float s = 0.f;
#pragma unroll
    for (int p = 0; p < 4; ++p) {
        const float pr = (float)counts[tid + p * 256] * (1.f / 32768.f);
        s = fmaf(pr, logf(pr + 1e-10f), s);
    }
#pragma unroll
    for (int off = 32; off; off >>= 1) s += __shfl_down(s, off, 64);
    if ((tid & 63) == 0) red[tid >> 6] = s;
    __syncthreads();
    if (tid == 0) {
        const float tot = red[0] + red[1] + red[2] + red[3];
        out[NELEM]     = loss_sum[0] * (1.25f / (float)NELEM);  // q_latent + 0.25*e_latent
        out[NELEM + 1] = expf(-tot);
    }
}

extern "C" void kernel_launch(void* const* d_in, const int* in_sizes, int n_in,
                              void* d_out, int out_size, void* d_ws, size_t ws_size,
                              hipStream_t stream) {
    const float* z = (const float*)d_in[0];
    const float* w = (const float*)d_in[1];
    float* out = (float*)d_out;

    float*        wsq      = (float*)d_ws;
    unsigned int* counts   = (unsigned int*)((char*)d_ws + 4096);
    float*        loss_sum = (float*)((char*)d_ws + 8192);

    // zero counts + loss accumulator (ws is re-poisoned to 0xAA each run)
    hipMemsetAsync((char*)d_ws + 4096, 0, 4100, stream);

    vq_wsq  <<<256, 256, 0, stream>>>(w, wsq);
    vq_main <<<512, 256, 0, stream>>>(z, w, wsq, counts, loss_sum, out);
    vq_final<<<1,   256, 0, stream>>>(counts, loss_sum, out);
}

// Round 2
// 130.699 us; speedup vs baseline: 4.0366x; 4.0366x over previous
//
#include <hip/hip_runtime.h>
#include <float.h>
#include <math.h>
#include <stdint.h>

// VQ-VAE VectorQuantizer — round 2: bf16 MFMA distance kernel
//
// z_e: (32, 256, 32, 32) fp32, weight: (1024, 256) fp32
// outputs concat: quantized_st (8388608) + loss (1) + perplexity (1)
//
// score[k][n] = wsq[k] - 2*w_k.z_n  via  mfma_f32_16x16x32_bf16:
//   A (M=16 codes)  = -2*w  (bf16, pre-packed in A-frag order by vq_pack)
//   B (N=16 z vecs) =  z    (bf16, packed in-register at kernel start)
//   C init          =  wsq[k]  -> accumulator is the score directly
//
// ws layout (bytes): [0,4096) wsq f32 | [4096,8192) counts u32
//                    [8192,8196) loss_sum f32 | [16384, 16384+524288) cbfrag bf16

#define NB   32
#define NC   256
#define NHW  1024
#define NK   1024
#define NELEM (NB*NC*NHW)   // 8388608

typedef __attribute__((ext_vector_type(8))) short bf16x8;   // 8 bf16 = 4 VGPRs
typedef __attribute__((ext_vector_type(4))) float f32x4;

__device__ __forceinline__ unsigned short f2bf(float f) {   // RTN fp32->bf16
    unsigned u = __float_as_uint(f);
    u += 0x7FFFu + ((u >> 16) & 1u);
    return (unsigned short)(u >> 16);
}

// ---------------- K1: codebook row squared norms ----------------
__global__ __launch_bounds__(256) void vq_wsq(const float* __restrict__ w,
                                              float* __restrict__ wsq) {
    const int lane = threadIdx.x & 63;
    const int wave = threadIdx.x >> 6;
    const int k = blockIdx.x * 4 + wave;
    const float* row = w + k * NC;
    float s = 0.f;
#pragma unroll
    for (int p = 0; p < 4; ++p) {
        float v = row[lane + p * 64];
        s = fmaf(v, v, s);
    }
#pragma unroll
    for (int off = 32; off; off >>= 1) s += __shfl_down(s, off, 64);
    if (lane == 0) wsq[k] = s;
}

// ---------------- K2: pack codebook into A-fragment order, scaled by -2 ----
// cb block (t, cc) is 1 KB: lane l holds A[m=l&15][k=cc*32+(l>>4)*8+j], j=0..7
__global__ __launch_bounds__(256) void vq_pack(const float* __restrict__ w,
                                               unsigned short* __restrict__ cb) {
    const int t = blockIdx.x;            // code tile 0..63
#pragma unroll
    for (int rep = 0; rep < 2; ++rep) {
        const int p = threadIdx.x + rep * 256;   // 0..511
        const int cc = p >> 6, l = p & 63;
        const int n = l & 15, quad = l >> 4;
        const float* src = w + (t * 16 + n) * NC + cc * 32 + quad * 8;
        const float4 f0 = *(const float4*)src;
        const float4 f1 = *(const float4*)(src + 4);
        union { unsigned short u[8]; uint4 v; } pk;
        pk.u[0] = f2bf(-2.f * f0.x); pk.u[1] = f2bf(-2.f * f0.y);
        pk.u[2] = f2bf(-2.f * f0.z); pk.u[3] = f2bf(-2.f * f0.w);
        pk.u[4] = f2bf(-2.f * f1.x); pk.u[5] = f2bf(-2.f * f1.y);
        pk.u[6] = f2bf(-2.f * f1.z); pk.u[7] = f2bf(-2.f * f1.w);
        *(uint4*)(cb + (size_t)t * 4096 + cc * 512 + l * 8) = pk.v;
    }
}

// ---------------- K3: main — MFMA argmin + gather + loss + histogram -------
// grid 256 blocks x 512 threads (8 waves). Block: 128 z vecs (1 m-tile/wave).
__global__ __launch_bounds__(512) void vq_main2(const float* __restrict__ z,
                                                const float* __restrict__ w,
                                                const float* __restrict__ wsq,
                                                const unsigned short* __restrict__ cb,
                                                unsigned int* __restrict__ counts,
                                                float* __restrict__ loss_sum,
                                                float* __restrict__ out) {
    __shared__ __align__(16) char cbuf[2][32768];   // double-buffered codebook chunk
    int*   fidx = (int*)cbuf[0];                    // aliased: used only after loop
    float* lred = (float*)(cbuf[0] + 1024);

    const int tid  = threadIdx.x;
    const int wv   = tid >> 6;            // wave 0..7
    const int lane = tid & 63;
    const int n    = lane & 15;
    const int quad = lane >> 4;
    const int bid  = blockIdx.x;
    const int b    = bid >> 3;            // batch image
    const int hw0  = (bid & 7) << 7;      // block's hw origin (128 rows)
    const int hwb  = hw0 + wv * 16;       // wave's m-tile hw base

    const float* zb = z + (size_t)b * (NC * NHW);

    // ---- Phase A: load this wave's 16 z vectors into B-fragments (bf16) ----
    bf16x8 bfr[8];
#pragma unroll
    for (int cc = 0; cc < 8; ++cc) {
        const float* zp = zb + (size_t)(cc * 32 + quad * 8) * NHW + hwb + n;
        union { unsigned short u[8]; bf16x8 v; } pk;
#pragma unroll
        for (int j = 0; j < 8; ++j) pk.u[j] = f2bf(zp[(size_t)j * NHW]);
        bfr[cc] = pk.v;
    }

    // ---- staging: chunk ch = 4 code tiles = 32 KB, wave stages 4 KB -------
    const char* cbb = (const char*)cb;
#define STAGE(ch)                                                              \
    {                                                                          \
        const char* gsrc = cbb + (size_t)(ch) * 32768 + wv * 4096 + lane * 16; \
        char* ldst = cbuf[(ch) & 1] + wv * 4096;                               \
        _Pragma("unroll")                                                      \
        for (int i = 0; i < 4; ++i) {                                          \
            __builtin_amdgcn_global_load_lds(                                  \
                (const __attribute__((address_space(1))) unsigned int*)        \
                    (uintptr_t)(gsrc + i * 1024),                              \
                (__attribute__((address_space(3))) unsigned int*)              \
                    (uint32_t)(uintptr_t)(ldst + i * 1024),                    \
                16, 0, 0);                                                     \
        }                                                                      \
    }

    float bestv = FLT_MAX;
    int   besti = 0;

    STAGE(0);
    for (int ch = 0; ch < 16; ++ch) {
        __syncthreads();                       // drains staging of buf[ch&1]
        if (ch + 1 < 16) STAGE(ch + 1);        // prefetch overlaps compute
        const char* bufc = cbuf[ch & 1];
#pragma unroll
        for (int tp = 0; tp < 2; ++tp) {       // 2 tile-pairs -> 2 indep chains
            const int tt0 = tp * 2, tt1 = tp * 2 + 1;
            const int kt0 = (ch * 4 + tt0) * 16;
            const int kt1 = kt0 + 16;
            f32x4 acc0 = *(const f32x4*)(wsq + kt0 + quad * 4);
            f32x4 acc1 = *(const f32x4*)(wsq + kt1 + quad * 4);
#pragma unroll
            for (int cc = 0; cc < 8; ++cc) {
                bf16x8 a0 = *(const bf16x8*)(bufc + (tt0 * 8 + cc) * 1024 + lane * 16);
                bf16x8 a1 = *(const bf16x8*)(bufc + (tt1 * 8 + cc) * 1024 + lane * 16);
                acc0 = __builtin_amdgcn_mfma_f32_16x16x32_bf16(a0, bfr[cc], acc0, 0, 0, 0);
                acc1 = __builtin_amdgcn_mfma_f32_16x16x32_bf16(a1, bfr[cc], acc1, 0, 0, 0);
            }
#pragma unroll
            for (int r = 0; r < 4; ++r) {
                const float v0 = acc0[r];
                if (v0 < bestv) { bestv = v0; besti = kt0 + quad * 4 + r; }
                const float v1 = acc1[r];
                if (v1 < bestv) { bestv = v1; besti = kt1 + quad * 4 + r; }
            }
        }
    }

    // ---- cross-quad argmin reduce (lanes n, n+16, n+32, n+48) -------------
#pragma unroll
    for (int off = 16; off <= 32; off <<= 1) {
        const float ov = __shfl_xor(bestv, off, 64);
        const int   ok = __shfl_xor(besti, off, 64);
        if (ov < bestv || (ov == bestv && ok < besti)) { bestv = ov; besti = ok; }
    }
    __syncthreads();                      // all waves done with cbuf -> fidx safe
    if (lane < 16) fidx[wv * 16 + lane] = besti;
    __syncthreads();
    if (tid < 128) atomicAdd(&counts[fidx[tid]], 1u);

    // ---- Phase 2: gather codebook rows, write quantized, accumulate loss --
    float lsum = 0.f;
    const int hwl = tid & 127;
    const int cg  = tid >> 7;             // 0..3 -> c range [cg*64, cg*64+64)
    const int myk = fidx[hwl];
    const float* wr  = w + myk * NC;
    const float* zp2 = zb + hw0 + hwl;
    float*       op  = out + (size_t)b * (NC * NHW) + hw0 + hwl;
#pragma unroll 4
    for (int p = 0; p < 16; ++p) {
        const int c0 = cg * 64 + p * 4;
        const float4 q4 = *(const float4*)(wr + c0);
        const float qa[4] = {q4.x, q4.y, q4.z, q4.w};
#pragma unroll
        for (int u = 0; u < 4; ++u) {
            const int c = c0 + u;
            const float zv = zp2[(size_t)c * NHW];
            const float d = qa[u] - zv;
            lsum = fmaf(d, d, lsum);
            op[(size_t)c * NHW] = qa[u];
        }
    }
#pragma unroll
    for (int off = 32; off; off >>= 1) lsum += __shfl_down(lsum, off, 64);
    if (lane == 0) lred[wv] = lsum;
    __syncthreads();
    if (tid == 0) {
        float t = 0.f;
#pragma unroll
        for (int i = 0; i < 8; ++i) t += lred[i];
        atomicAdd(loss_sum, t);
    }
}

// ---------------- K4: finalize loss + perplexity ----------------
__global__ __launch_bounds__(256) void vq_final(const unsigned int* __restrict__ counts,
                                                const float* __restrict__ loss_sum,
                                                float* __restrict__ out) {
    __shared__ float red[4];
    const int tid = threadIdx.x;
    float s = 0.f;
#pragma unroll
    for (int p = 0; p < 4; ++p) {
        const float pr = (float)counts[tid + p * 256] * (1.f / 32768.f);
        s = fmaf(pr, logf(pr + 1e-10f), s);
    }
#pragma unroll
    for (int off = 32; off; off >>= 1) s += __shfl_down(s, off, 64);
    if ((tid & 63) == 0) red[tid >> 6] = s;
    __syncthreads();
    if (tid == 0) {
        const float tot = red[0] + red[1] + red[2] + red[3];
        out[NELEM]     = loss_sum[0] * (1.25f / (float)NELEM);
        out[NELEM + 1] = expf(-tot);
    }
}

extern "C" void kernel_launch(void* const* d_in, const int* in_sizes, int n_in,
                              void* d_out, int out_size, void* d_ws, size_t ws_size,
                              hipStream_t stream) {
    const float* z = (const float*)d_in[0];
    const float* w = (const float*)d_in[1];
    float* out = (float*)d_out;

    float*          wsq      = (float*)d_ws;
    unsigned int*   counts   = (unsigned int*)((char*)d_ws + 4096);
    float*          loss_sum = (float*)((char*)d_ws + 8192);
    unsigned short* cbfrag   = (unsigned short*)((char*)d_ws + 16384);  // 512 KB

    hipMemsetAsync((char*)d_ws + 4096, 0, 4100, stream);  // counts + loss_sum

    vq_wsq  <<<256, 256, 0, stream>>>(w, wsq);
    vq_pack <<<64,  256, 0, stream>>>(w, cbfrag);
    vq_main2<<<256, 512, 0, stream>>>(z, w, wsq, cbfrag, counts, loss_sum, out);
    vq_final<<<1,   256, 0, stream>>>(counts, loss_sum, out);
}